// Round 1
// 584.024 us; speedup vs baseline: 1.6921x; 1.6921x over previous
//
#include <hip/hip_runtime.h>

// EdgeAggregate: out[E,64] = segment_sum(feat[nbr[:,1]], nbr[:,0]) @ K[64,64] + bias
//
// R2 theory: k_build's 4M scattered 4B csr stores each paid a full 64B HBM
// line write-back (WRITE_SIZE 257MB == 4M*64B, measured) -> ~350us. Replace
// hist+build with an LDS-staged bucketed counting sort whose global writes
// are line-coalesced: bhist -> bscan -> partition (pack (src<<10)|dst_local,
// bin in LDS, flush contiguous runs) -> bucket (per-dst hist/scan in LDS,
// emits offs[] AND csr[] with fully coalesced writes). k_agg unchanged.

#define FD 64
#define BKT_SHIFT 10
#define BKT_MAX 512            // requires NBKT <= 512  (E <= 524288)
#define TILE_A 8192            // pairs per partition block
#define CAP_B 12288            // LDS csr stage capacity per bucket

// ---------------- new build pipeline ----------------

// bucket histogram: LDS-aggregated, 512 global atomics per block max
__global__ __launch_bounds__(256) void k_bhist(const int2* __restrict__ nbr,
                                               int* __restrict__ bcnt, int P) {
    __shared__ int h[BKT_MAX];
    const int t = threadIdx.x;
    for (int i = t; i < BKT_MAX; i += 256) h[i] = 0;
    __syncthreads();
    const int base = blockIdx.x * 4096;
#pragma unroll
    for (int j = 0; j < 16; ++j) {
        int p = base + j * 256 + t;
        if (p < P) atomicAdd(&h[nbr[p].x >> BKT_SHIFT], 1);
    }
    __syncthreads();
    for (int i = t; i < BKT_MAX; i += 256) {
        int v = h[i];
        if (v) atomicAdd(&bcnt[i], v);
    }
}

// single block: exclusive scan of bucket counts -> bbase; init bcur = bbase.
// bcnt may alias bcur (each element read by its own thread before overwrite).
__global__ __launch_bounds__(512) void k_bscan(const int* __restrict__ bcnt,
                                               int* __restrict__ bbase,
                                               int* __restrict__ bcur,
                                               int NBKT, int P) {
    __shared__ int s[BKT_MAX];
    const int t = threadIdx.x;
    s[t] = (t < NBKT) ? bcnt[t] : 0;
    __syncthreads();
    int orig = s[t];
    for (int off = 1; off < BKT_MAX; off <<= 1) {
        int v = (t >= off) ? s[t - off] : 0;
        __syncthreads();
        s[t] += v;
        __syncthreads();
    }
    int ex = s[t] - orig;
    if (t < NBKT) {
        bbase[t] = ex;
        bcur[t] = ex;
    }
    if (t == NBKT - 1) bbase[NBKT] = s[t];  // == P
    (void)P;
}

// partition pairs into bucket-major order. Global writes are contiguous
// per-(block,bucket) runs (avg ~17 ints) instead of scattered 4B stores.
__global__ __launch_bounds__(256) void k_partition(const int2* __restrict__ nbr,
                                                   int* __restrict__ bcur,
                                                   int* __restrict__ part, int P) {
    __shared__ int hist[BKT_MAX];
    __shared__ int off[BKT_MAX];       // exclusive offsets (preserved for flush)
    __shared__ int curs[BKT_MAX];      // scatter cursors
    __shared__ int rb[BKT_MAX];        // reserved global run base
    __shared__ int tsum[256];
    __shared__ int stage_v[TILE_A];
    __shared__ unsigned short stage_b[TILE_A];

    const int t = threadIdx.x;
    const int base = blockIdx.x * TILE_A;

    for (int i = t; i < BKT_MAX; i += 256) hist[i] = 0;
    __syncthreads();

    // phase 1: local histogram
#pragma unroll
    for (int j = 0; j < TILE_A / 256; ++j) {
        int p = base + j * 256 + t;
        if (p < P) atomicAdd(&hist[nbr[p].x >> BKT_SHIFT], 1);
    }
    __syncthreads();

    // phase 2: scan 512 entries with 256 threads
    int h0 = hist[2 * t], h1 = hist[2 * t + 1];
    int pairsum = h0 + h1;
    tsum[t] = pairsum;
    __syncthreads();
    for (int o = 1; o < 256; o <<= 1) {
        int v = (t >= o) ? tsum[t - o] : 0;
        __syncthreads();
        tsum[t] += v;
        __syncthreads();
    }
    int ex = tsum[t] - pairsum;
    off[2 * t] = ex;
    off[2 * t + 1] = ex + h0;
    curs[2 * t] = ex;
    curs[2 * t + 1] = ex + h0;
    __syncthreads();

    // phase 3: reserve global space (one atomic per nonempty bucket) and
    // phase 4: scatter into LDS stage
    for (int i = t; i < BKT_MAX; i += 256) {
        int c = hist[i];
        rb[i] = c ? atomicAdd(&bcur[i], c) : 0;
    }
#pragma unroll
    for (int j = 0; j < TILE_A / 256; ++j) {
        int p = base + j * 256 + t;
        if (p < P) {
            int2 e = nbr[p];
            int b = e.x >> BKT_SHIFT;
            int v = (e.y << BKT_SHIFT) | (e.x & ((1 << BKT_SHIFT) - 1));
            int pos = atomicAdd(&curs[b], 1);
            stage_v[pos] = v;
            stage_b[pos] = (unsigned short)b;
        }
    }
    __syncthreads();

    // phase 5: flush — consecutive idx -> consecutive global addresses
    int n = min(TILE_A, P - base);
    for (int idx = t; idx < n; idx += 256) {
        int b = stage_b[idx];
        part[rb[b] + (idx - off[b])] = stage_v[idx];
    }
}

// one block per bucket: per-dst hist + scan (emits offs[]), LDS scatter,
// coalesced csr flush.
__global__ __launch_bounds__(256) void k_bucket(const int* __restrict__ part,
                                                const int* __restrict__ bbase,
                                                int* __restrict__ offs,
                                                int* __restrict__ csr,
                                                int E, int P, int NBKT) {
    __shared__ int hist[1 << BKT_SHIFT];
    __shared__ int cur[1 << BKT_SHIFT];
    __shared__ int tsum[256];
    __shared__ int stage[CAP_B];

    const int b = blockIdx.x;
    const int t = threadIdx.x;
    const int base = bbase[b];
    const int n = bbase[b + 1] - base;
    const int ND = 1 << BKT_SHIFT;

    for (int i = t; i < ND; i += 256) hist[i] = 0;
    __syncthreads();

    for (int idx = t; idx < n; idx += 256)
        atomicAdd(&hist[part[base + idx] & (ND - 1)], 1);
    __syncthreads();

    // scan ND=1024 entries with 256 threads (4 each)
    int h[4];
    int s = 0;
#pragma unroll
    for (int j = 0; j < 4; ++j) {
        h[j] = hist[4 * t + j];
        s += h[j];
    }
    tsum[t] = s;
    __syncthreads();
    for (int o = 1; o < 256; o <<= 1) {
        int v = (t >= o) ? tsum[t - o] : 0;
        __syncthreads();
        tsum[t] += v;
        __syncthreads();
    }
    int run = tsum[t] - s;
#pragma unroll
    for (int j = 0; j < 4; ++j) {
        int d = (b << BKT_SHIFT) + 4 * t + j;
        cur[4 * t + j] = run;
        if (d < E) offs[d] = base + run;
        run += h[j];
    }
    if (b == NBKT - 1 && t == 0) offs[E] = P;
    __syncthreads();

    if (n <= CAP_B) {
        for (int idx = t; idx < n; idx += 256) {
            int v = part[base + idx];
            int p = atomicAdd(&cur[v & (ND - 1)], 1);
            stage[p] = v >> BKT_SHIFT;
        }
        __syncthreads();
        for (int idx = t; idx < n; idx += 256) csr[base + idx] = stage[idx];
    } else {
        // overflow guard (statistically unreachable for uniform input)
        for (int idx = t; idx < n; idx += 256) {
            int v = part[base + idx];
            int p = atomicAdd(&cur[v & (ND - 1)], 1);
            csr[base + p] = v >> BKT_SHIFT;
        }
    }
}

// ---------------- old CSR pipeline (fallback #1, unchanged) ----------------

__global__ __launch_bounds__(256) void k_hist(const int* __restrict__ nbr,
                                              int* __restrict__ cnt, int P) {
    int p = blockIdx.x * 256 + threadIdx.x;
    if (p < P) atomicAdd(&cnt[nbr[2 * p]], 1);
}

__global__ __launch_bounds__(256) void k_blocksum(const int* __restrict__ cnt,
                                                  int* __restrict__ bsum, int E) {
    int base = blockIdx.x * 1024;
    int t = threadIdx.x;
    int s = 0;
#pragma unroll
    for (int j = 0; j < 4; ++j) {
        int e = base + t + j * 256;
        if (e < E) s += cnt[e];
    }
    for (int off = 32; off; off >>= 1) s += __shfl_down(s, off, 64);
    __shared__ int wsum[4];
    int wid = t >> 6, lane = t & 63;
    if (lane == 0) wsum[wid] = s;
    __syncthreads();
    if (t == 0) bsum[blockIdx.x] = wsum[0] + wsum[1] + wsum[2] + wsum[3];
}

__global__ __launch_bounds__(1024) void k_scan_bsum(int* bsum, int NB) {
    __shared__ int s[1024];
    int t = threadIdx.x;
    s[t] = (t < NB) ? bsum[t] : 0;
    __syncthreads();
    int orig = s[t];
    for (int off = 1; off < 1024; off <<= 1) {
        int v = (t >= off) ? s[t - off] : 0;
        __syncthreads();
        s[t] += v;
        __syncthreads();
    }
    if (t < NB) bsum[t] = s[t] - orig;
}

__global__ __launch_bounds__(256) void k_scan_write(const int* __restrict__ cnt,
                                                    const int* __restrict__ boff,
                                                    int* __restrict__ offs,
                                                    int* __restrict__ cur,
                                                    int E) {
    __shared__ int tsum[256];
    int b = blockIdx.x, t = threadIdx.x;
    int base = b * 1024 + t * 4;
    int c[4];
#pragma unroll
    for (int j = 0; j < 4; ++j) {
        int e = base + j;
        c[j] = (e < E) ? cnt[e] : 0;
    }
    int local = c[0] + c[1] + c[2] + c[3];
    tsum[t] = local;
    __syncthreads();
    for (int off = 1; off < 256; off <<= 1) {
        int v = (t >= off) ? tsum[t - off] : 0;
        __syncthreads();
        tsum[t] += v;
        __syncthreads();
    }
    int run = tsum[t] - local + boff[b];
#pragma unroll
    for (int j = 0; j < 4; ++j) {
        int e = base + j;
        if (e < E) {
            offs[e] = run;
            cur[e] = run;
            run += c[j];
            if (e == E - 1) offs[E] = run;
        }
    }
}

__global__ __launch_bounds__(256) void k_build(const int* __restrict__ nbr,
                                               int* __restrict__ cur,
                                               int* __restrict__ csr, int P) {
    int p = blockIdx.x * 256 + threadIdx.x;
    if (p < P) {
        int dst = nbr[2 * p + 0];
        int src = nbr[2 * p + 1];
        int pos = atomicAdd(&cur[dst], 1);
        csr[pos] = src;
    }
}

// ---------------- aggregate + transform (unchanged) ----------------

__global__ __launch_bounds__(256) void k_agg(const float* __restrict__ feat,
                                             const int* __restrict__ offs,
                                             const int* __restrict__ csr,
                                             const float* __restrict__ Kmat,
                                             const float* __restrict__ bias,
                                             float* __restrict__ out, int E) {
    __shared__ float xr[4 * FD];
    const int lane = threadIdx.x & 63;
    const int wid = threadIdx.x >> 6;

    float kcol[FD];
#pragma unroll
    for (int d = 0; d < FD; ++d) kcol[d] = Kmat[d * FD + lane];
    const float b = bias[lane];

    const int wv = __builtin_amdgcn_readfirstlane((int)blockIdx.x * 4 + wid);
    const int nw = (int)gridDim.x * 4;
    float* const xw = &xr[wid * FD];

    for (int e = wv; e < E; e += nw) {
        const int beg = offs[e], end = offs[e + 1];
        float acc = 0.f;
        int i = beg;
        for (; i + 1 < end; i += 2) {
            int s0 = csr[i], s1 = csr[i + 1];
            float v0 = feat[(size_t)s0 * FD + lane];
            float v1 = feat[(size_t)s1 * FD + lane];
            acc += v0;
            acc += v1;
        }
        if (i < end) acc += feat[(size_t)csr[i] * FD + lane];

        xw[lane] = acc;
        float o = b;
        const float4* xp = (const float4*)xw;
#pragma unroll
        for (int j = 0; j < FD / 4; ++j) {
            float4 q = xp[j];
            o += q.x * kcol[4 * j + 0] + q.y * kcol[4 * j + 1] +
                 q.z * kcol[4 * j + 2] + q.w * kcol[4 * j + 3];
        }
        out[(size_t)e * FD + lane] = o;
    }
}

// ---------------- fallback #2 (atomic scatter) ----------------

__global__ __launch_bounds__(256) void ea_scatter(const float* __restrict__ feat,
                                                  const int* __restrict__ nbr,
                                                  float* __restrict__ agg, int P) {
    const int lane = threadIdx.x & 63;
    const int pair = __builtin_amdgcn_readfirstlane(
        (int)blockIdx.x * 4 + ((int)threadIdx.x >> 6));
    if (pair < P) {
        const int dst = nbr[2 * pair + 0];
        const int src = nbr[2 * pair + 1];
        atomicAdd(&agg[(size_t)dst * FD + lane], feat[(size_t)src * FD + lane]);
    }
}

__global__ __launch_bounds__(256) void ea_transform(float* __restrict__ io,
                                                    const float* __restrict__ Kmat,
                                                    const float* __restrict__ bias,
                                                    int E) {
    const int lane = threadIdx.x & 63;
    float kcol[FD];
#pragma unroll
    for (int d = 0; d < FD; ++d) kcol[d] = Kmat[d * FD + lane];
    const float b = bias[lane];
    const int wv = __builtin_amdgcn_readfirstlane(
        (int)blockIdx.x * 4 + ((int)threadIdx.x >> 6));
    const int nw = (int)gridDim.x * 4;
    for (int e = wv; e < E; e += nw) {
        const float* __restrict__ row = io + (size_t)e * FD;
        float acc = b;
#pragma unroll
        for (int d = 0; d < FD; ++d) acc += row[d] * kcol[d];
        io[(size_t)e * FD + lane] = acc;
    }
}

// ---------------- launcher ----------------

extern "C" void kernel_launch(void* const* d_in, const int* in_sizes, int n_in,
                              void* d_out, int out_size, void* d_ws, size_t ws_size,
                              hipStream_t stream) {
    const float* feat = (const float*)d_in[0];
    const int* nbr = (const int*)d_in[1];
    const float* Kmat = (const float*)d_in[2];
    const float* bias = (const float*)d_in[3];
    float* out = (float*)d_out;

    const int E = in_sizes[0] / FD;  // 500000
    const int P = in_sizes[1] / 2;   // 4000000
    const int NBKT = (E + (1 << BKT_SHIFT) - 1) >> BKT_SHIFT;
    const int NB = (E + 1023) / 1024;

    const size_t need_new =
        ((size_t)(E + 1) + (BKT_MAX + 1) + BKT_MAX + 2 * (size_t)P) * sizeof(int);
    const size_t need_old =
        ((size_t)E + (size_t)(E + 1) + 1024 + (size_t)P) * sizeof(int);

    if (NBKT <= BKT_MAX && ws_size >= need_new) {
        // ---- new bucketed counting-sort build ----
        int* offs = (int*)d_ws;              // E+1
        int* bbase = offs + (E + 1);         // BKT_MAX+1
        int* bcur = bbase + (BKT_MAX + 1);   // BKT_MAX (doubles as bcnt)
        int* part = bcur + BKT_MAX;          // P
        int* csr = part + P;                 // P

        hipMemsetAsync(bcur, 0, BKT_MAX * sizeof(int), stream);
        k_bhist<<<(P + 4095) / 4096, 256, 0, stream>>>((const int2*)nbr, bcur, P);
        k_bscan<<<1, BKT_MAX, 0, stream>>>(bcur, bbase, bcur, NBKT, P);
        k_partition<<<(P + TILE_A - 1) / TILE_A, 256, 0, stream>>>(
            (const int2*)nbr, bcur, part, P);
        k_bucket<<<NBKT, 256, 0, stream>>>(part, bbase, offs, csr, E, P, NBKT);
        k_agg<<<4096, 256, 0, stream>>>(feat, offs, csr, Kmat, bias, out, E);
    } else if (ws_size >= need_old && NB <= 1024) {
        // ---- old CSR pipeline ----
        int* cur = (int*)d_ws;
        int* offs = cur + E;
        int* bsum = offs + E + 1;
        int* csr = bsum + 1024;

        hipMemsetAsync(cur, 0, (size_t)E * sizeof(int), stream);
        k_hist<<<(P + 255) / 256, 256, 0, stream>>>(nbr, cur, P);
        k_blocksum<<<NB, 256, 0, stream>>>(cur, bsum, E);
        k_scan_bsum<<<1, 1024, 0, stream>>>(bsum, NB);
        k_scan_write<<<NB, 256, 0, stream>>>(cur, bsum, offs, cur, E);
        k_build<<<(P + 255) / 256, 256, 0, stream>>>(nbr, cur, csr, P);
        k_agg<<<4096, 256, 0, stream>>>(feat, offs, csr, Kmat, bias, out, E);
    } else {
        // ---- atomic fallback ----
        hipMemsetAsync(d_out, 0, (size_t)out_size * sizeof(float), stream);
        ea_scatter<<<(P + 3) / 4, 256, 0, stream>>>(feat, nbr, out, P);
        ea_transform<<<2048, 256, 0, stream>>>(out, Kmat, bias, E);
    }
}

// Round 2
// 534.354 us; speedup vs baseline: 1.8494x; 1.0930x over previous
//
#include <hip/hip_runtime.h>

// EdgeAggregate: out[E,64] = segment_sum(feat[nbr[:,1]], nbr[:,0]) @ K[64,64] + bias
//
// R2: bucketed counting-sort build (line-coalesced writes) -- 988 -> 584 us.
// R3 theory: k_agg (326 us) is latency/MLP-bound: 2.0 TB/s HBM, VALU 28%,
// occupancy 48% -- nothing saturated. Each wave held only 2x256B gathers in
// flight. New gather: each lane loads float4, 16 lanes/row -> one instruction
// gathers 4 rows (1KB); unroll x2 = 2KB in flight per wave (4x before).
// Cross-group reduce via 8 shfl_xor adds. Plus nontemporal out-stores so the
// 128MB write stream stops evicting the 128MB feat array from the 256MB LLC.

#define FD 64
#define BKT_SHIFT 10
#define BKT_MAX 512            // requires NBKT <= 512  (E <= 524288)
#define TILE_A 8192            // pairs per partition block
#define CAP_B 12288            // LDS csr stage capacity per bucket

// ---------------- build pipeline (unchanged from R2) ----------------

__global__ __launch_bounds__(256) void k_bhist(const int2* __restrict__ nbr,
                                               int* __restrict__ bcnt, int P) {
    __shared__ int h[BKT_MAX];
    const int t = threadIdx.x;
    for (int i = t; i < BKT_MAX; i += 256) h[i] = 0;
    __syncthreads();
    const int base = blockIdx.x * 4096;
#pragma unroll
    for (int j = 0; j < 16; ++j) {
        int p = base + j * 256 + t;
        if (p < P) atomicAdd(&h[nbr[p].x >> BKT_SHIFT], 1);
    }
    __syncthreads();
    for (int i = t; i < BKT_MAX; i += 256) {
        int v = h[i];
        if (v) atomicAdd(&bcnt[i], v);
    }
}

__global__ __launch_bounds__(512) void k_bscan(const int* __restrict__ bcnt,
                                               int* __restrict__ bbase,
                                               int* __restrict__ bcur,
                                               int NBKT, int P) {
    __shared__ int s[BKT_MAX];
    const int t = threadIdx.x;
    s[t] = (t < NBKT) ? bcnt[t] : 0;
    __syncthreads();
    int orig = s[t];
    for (int off = 1; off < BKT_MAX; off <<= 1) {
        int v = (t >= off) ? s[t - off] : 0;
        __syncthreads();
        s[t] += v;
        __syncthreads();
    }
    int ex = s[t] - orig;
    if (t < NBKT) {
        bbase[t] = ex;
        bcur[t] = ex;
    }
    if (t == NBKT - 1) bbase[NBKT] = s[t];  // == P
    (void)P;
}

__global__ __launch_bounds__(256) void k_partition(const int2* __restrict__ nbr,
                                                   int* __restrict__ bcur,
                                                   int* __restrict__ part, int P) {
    __shared__ int hist[BKT_MAX];
    __shared__ int off[BKT_MAX];
    __shared__ int curs[BKT_MAX];
    __shared__ int rb[BKT_MAX];
    __shared__ int tsum[256];
    __shared__ int stage_v[TILE_A];
    __shared__ unsigned short stage_b[TILE_A];

    const int t = threadIdx.x;
    const int base = blockIdx.x * TILE_A;

    for (int i = t; i < BKT_MAX; i += 256) hist[i] = 0;
    __syncthreads();

#pragma unroll
    for (int j = 0; j < TILE_A / 256; ++j) {
        int p = base + j * 256 + t;
        if (p < P) atomicAdd(&hist[nbr[p].x >> BKT_SHIFT], 1);
    }
    __syncthreads();

    int h0 = hist[2 * t], h1 = hist[2 * t + 1];
    int pairsum = h0 + h1;
    tsum[t] = pairsum;
    __syncthreads();
    for (int o = 1; o < 256; o <<= 1) {
        int v = (t >= o) ? tsum[t - o] : 0;
        __syncthreads();
        tsum[t] += v;
        __syncthreads();
    }
    int ex = tsum[t] - pairsum;
    off[2 * t] = ex;
    off[2 * t + 1] = ex + h0;
    curs[2 * t] = ex;
    curs[2 * t + 1] = ex + h0;
    __syncthreads();

    for (int i = t; i < BKT_MAX; i += 256) {
        int c = hist[i];
        rb[i] = c ? atomicAdd(&bcur[i], c) : 0;
    }
#pragma unroll
    for (int j = 0; j < TILE_A / 256; ++j) {
        int p = base + j * 256 + t;
        if (p < P) {
            int2 e = nbr[p];
            int b = e.x >> BKT_SHIFT;
            int v = (e.y << BKT_SHIFT) | (e.x & ((1 << BKT_SHIFT) - 1));
            int pos = atomicAdd(&curs[b], 1);
            stage_v[pos] = v;
            stage_b[pos] = (unsigned short)b;
        }
    }
    __syncthreads();

    int n = min(TILE_A, P - base);
    for (int idx = t; idx < n; idx += 256) {
        int b = stage_b[idx];
        part[rb[b] + (idx - off[b])] = stage_v[idx];
    }
}

__global__ __launch_bounds__(256) void k_bucket(const int* __restrict__ part,
                                                const int* __restrict__ bbase,
                                                int* __restrict__ offs,
                                                int* __restrict__ csr,
                                                int E, int P, int NBKT) {
    __shared__ int hist[1 << BKT_SHIFT];
    __shared__ int cur[1 << BKT_SHIFT];
    __shared__ int tsum[256];
    __shared__ int stage[CAP_B];

    const int b = blockIdx.x;
    const int t = threadIdx.x;
    const int base = bbase[b];
    const int n = bbase[b + 1] - base;
    const int ND = 1 << BKT_SHIFT;

    for (int i = t; i < ND; i += 256) hist[i] = 0;
    __syncthreads();

    for (int idx = t; idx < n; idx += 256)
        atomicAdd(&hist[part[base + idx] & (ND - 1)], 1);
    __syncthreads();

    int h[4];
    int s = 0;
#pragma unroll
    for (int j = 0; j < 4; ++j) {
        h[j] = hist[4 * t + j];
        s += h[j];
    }
    tsum[t] = s;
    __syncthreads();
    for (int o = 1; o < 256; o <<= 1) {
        int v = (t >= o) ? tsum[t - o] : 0;
        __syncthreads();
        tsum[t] += v;
        __syncthreads();
    }
    int run = tsum[t] - s;
#pragma unroll
    for (int j = 0; j < 4; ++j) {
        int d = (b << BKT_SHIFT) + 4 * t + j;
        cur[4 * t + j] = run;
        if (d < E) offs[d] = base + run;
        run += h[j];
    }
    if (b == NBKT - 1 && t == 0) offs[E] = P;
    __syncthreads();

    if (n <= CAP_B) {
        for (int idx = t; idx < n; idx += 256) {
            int v = part[base + idx];
            int p = atomicAdd(&cur[v & (ND - 1)], 1);
            stage[p] = v >> BKT_SHIFT;
        }
        __syncthreads();
        for (int idx = t; idx < n; idx += 256) csr[base + idx] = stage[idx];
    } else {
        for (int idx = t; idx < n; idx += 256) {
            int v = part[base + idx];
            int p = atomicAdd(&cur[v & (ND - 1)], 1);
            csr[base + p] = v >> BKT_SHIFT;
        }
    }
}

// ---------------- aggregate + transform (R3: float4 gather) ----------------

// One wave per dst row. Gather: lane loads float4; 16-lane group g covers one
// src row; one wave instruction gathers 4 rows (1KB), unrolled x2 -> 2KB in
// flight. Cross-group combine: shfl_xor 16/32. Transform via per-wave LDS
// transpose as before. Output stored nontemporally (keep feat in LLC).
__global__ __launch_bounds__(256) void k_agg(const float* __restrict__ feat,
                                             const int* __restrict__ offs,
                                             const int* __restrict__ csr,
                                             const float* __restrict__ Kmat,
                                             const float* __restrict__ bias,
                                             float* __restrict__ out, int E) {
    __shared__ float xr[4][FD];
    const int lane = threadIdx.x & 63;
    const int wid = threadIdx.x >> 6;
    const int g = lane >> 4;    // src-slot within a 4-wide gather step
    const int gl = lane & 15;   // float4 slot within the row

    float kcol[FD];
#pragma unroll
    for (int d = 0; d < FD; ++d) kcol[d] = Kmat[d * FD + lane];
    const float b = bias[lane];

    const int wv = __builtin_amdgcn_readfirstlane((int)blockIdx.x * 4 + wid);
    const int nw = (int)gridDim.x * 4;
    float4* const xw4 = (float4*)&xr[wid][0];

    for (int e = wv; e < E; e += nw) {
        const int beg = offs[e], end = offs[e + 1];
        float4 a = {0.f, 0.f, 0.f, 0.f};
        int i = beg;
        for (; i + 8 <= end; i += 8) {
            int s0 = csr[i + g];
            int s1 = csr[i + 4 + g];
            const float4 v0 =
                *(const float4*)&feat[(size_t)s0 * FD + 4 * gl];
            const float4 v1 =
                *(const float4*)&feat[(size_t)s1 * FD + 4 * gl];
            a.x += v0.x + v1.x;
            a.y += v0.y + v1.y;
            a.z += v0.z + v1.z;
            a.w += v0.w + v1.w;
        }
        for (; i < end; i += 4) {
            int idx = i + g;
            if (idx < end) {
                int s = csr[idx];
                const float4 v =
                    *(const float4*)&feat[(size_t)s * FD + 4 * gl];
                a.x += v.x;
                a.y += v.y;
                a.z += v.z;
                a.w += v.w;
            }
        }
        // combine the 4 src-slots: lanes 16 and 32 apart hold partials of the
        // same feature slice
        a.x += __shfl_xor(a.x, 16, 64);
        a.y += __shfl_xor(a.y, 16, 64);
        a.z += __shfl_xor(a.z, 16, 64);
        a.w += __shfl_xor(a.w, 16, 64);
        a.x += __shfl_xor(a.x, 32, 64);
        a.y += __shfl_xor(a.y, 32, 64);
        a.z += __shfl_xor(a.z, 32, 64);
        a.w += __shfl_xor(a.w, 32, 64);

        // transpose through private LDS strip (same wave writes then reads)
        if (g == 0) xw4[gl] = a;
        float o = b;
        const float4* xp = (const float4*)&xr[wid][0];
#pragma unroll
        for (int j = 0; j < FD / 4; ++j) {
            float4 q = xp[j];
            o += q.x * kcol[4 * j + 0] + q.y * kcol[4 * j + 1] +
                 q.z * kcol[4 * j + 2] + q.w * kcol[4 * j + 3];
        }
        __builtin_nontemporal_store(o, &out[(size_t)e * FD + lane]);
    }
}

// ---------------- old CSR pipeline (fallback #1, unchanged) ----------------

__global__ __launch_bounds__(256) void k_hist(const int* __restrict__ nbr,
                                              int* __restrict__ cnt, int P) {
    int p = blockIdx.x * 256 + threadIdx.x;
    if (p < P) atomicAdd(&cnt[nbr[2 * p]], 1);
}

__global__ __launch_bounds__(256) void k_blocksum(const int* __restrict__ cnt,
                                                  int* __restrict__ bsum, int E) {
    int base = blockIdx.x * 1024;
    int t = threadIdx.x;
    int s = 0;
#pragma unroll
    for (int j = 0; j < 4; ++j) {
        int e = base + t + j * 256;
        if (e < E) s += cnt[e];
    }
    for (int off = 32; off; off >>= 1) s += __shfl_down(s, off, 64);
    __shared__ int wsum[4];
    int wid = t >> 6, lane = t & 63;
    if (lane == 0) wsum[wid] = s;
    __syncthreads();
    if (t == 0) bsum[blockIdx.x] = wsum[0] + wsum[1] + wsum[2] + wsum[3];
}

__global__ __launch_bounds__(1024) void k_scan_bsum(int* bsum, int NB) {
    __shared__ int s[1024];
    int t = threadIdx.x;
    s[t] = (t < NB) ? bsum[t] : 0;
    __syncthreads();
    int orig = s[t];
    for (int off = 1; off < 1024; off <<= 1) {
        int v = (t >= off) ? s[t - off] : 0;
        __syncthreads();
        s[t] += v;
        __syncthreads();
    }
    if (t < NB) bsum[t] = s[t] - orig;
}

__global__ __launch_bounds__(256) void k_scan_write(const int* __restrict__ cnt,
                                                    const int* __restrict__ boff,
                                                    int* __restrict__ offs,
                                                    int* __restrict__ cur,
                                                    int E) {
    __shared__ int tsum[256];
    int b = blockIdx.x, t = threadIdx.x;
    int base = b * 1024 + t * 4;
    int c[4];
#pragma unroll
    for (int j = 0; j < 4; ++j) {
        int e = base + j;
        c[j] = (e < E) ? cnt[e] : 0;
    }
    int local = c[0] + c[1] + c[2] + c[3];
    tsum[t] = local;
    __syncthreads();
    for (int off = 1; off < 256; off <<= 1) {
        int v = (t >= off) ? tsum[t - off] : 0;
        __syncthreads();
        tsum[t] += v;
        __syncthreads();
    }
    int run = tsum[t] - local + boff[b];
#pragma unroll
    for (int j = 0; j < 4; ++j) {
        int e = base + j;
        if (e < E) {
            offs[e] = run;
            cur[e] = run;
            run += c[j];
            if (e == E - 1) offs[E] = run;
        }
    }
}

__global__ __launch_bounds__(256) void k_build(const int* __restrict__ nbr,
                                               int* __restrict__ cur,
                                               int* __restrict__ csr, int P) {
    int p = blockIdx.x * 256 + threadIdx.x;
    if (p < P) {
        int dst = nbr[2 * p + 0];
        int src = nbr[2 * p + 1];
        int pos = atomicAdd(&cur[dst], 1);
        csr[pos] = src;
    }
}

// ---------------- fallback #2 (atomic scatter) ----------------

__global__ __launch_bounds__(256) void ea_scatter(const float* __restrict__ feat,
                                                  const int* __restrict__ nbr,
                                                  float* __restrict__ agg, int P) {
    const int lane = threadIdx.x & 63;
    const int pair = __builtin_amdgcn_readfirstlane(
        (int)blockIdx.x * 4 + ((int)threadIdx.x >> 6));
    if (pair < P) {
        const int dst = nbr[2 * pair + 0];
        const int src = nbr[2 * pair + 1];
        atomicAdd(&agg[(size_t)dst * FD + lane], feat[(size_t)src * FD + lane]);
    }
}

__global__ __launch_bounds__(256) void ea_transform(float* __restrict__ io,
                                                    const float* __restrict__ Kmat,
                                                    const float* __restrict__ bias,
                                                    int E) {
    const int lane = threadIdx.x & 63;
    float kcol[FD];
#pragma unroll
    for (int d = 0; d < FD; ++d) kcol[d] = Kmat[d * FD + lane];
    const float b = bias[lane];
    const int wv = __builtin_amdgcn_readfirstlane(
        (int)blockIdx.x * 4 + ((int)threadIdx.x >> 6));
    const int nw = (int)gridDim.x * 4;
    for (int e = wv; e < E; e += nw) {
        const float* __restrict__ row = io + (size_t)e * FD;
        float acc = b;
#pragma unroll
        for (int d = 0; d < FD; ++d) acc += row[d] * kcol[d];
        io[(size_t)e * FD + lane] = acc;
    }
}

// ---------------- launcher ----------------

extern "C" void kernel_launch(void* const* d_in, const int* in_sizes, int n_in,
                              void* d_out, int out_size, void* d_ws, size_t ws_size,
                              hipStream_t stream) {
    const float* feat = (const float*)d_in[0];
    const int* nbr = (const int*)d_in[1];
    const float* Kmat = (const float*)d_in[2];
    const float* bias = (const float*)d_in[3];
    float* out = (float*)d_out;

    const int E = in_sizes[0] / FD;  // 500000
    const int P = in_sizes[1] / 2;   // 4000000
    const int NBKT = (E + (1 << BKT_SHIFT) - 1) >> BKT_SHIFT;
    const int NB = (E + 1023) / 1024;

    const size_t need_new =
        ((size_t)(E + 1) + (BKT_MAX + 1) + BKT_MAX + 2 * (size_t)P) * sizeof(int);
    const size_t need_old =
        ((size_t)E + (size_t)(E + 1) + 1024 + (size_t)P) * sizeof(int);

    if (NBKT <= BKT_MAX && ws_size >= need_new) {
        int* offs = (int*)d_ws;              // E+1
        int* bbase = offs + (E + 1);         // BKT_MAX+1
        int* bcur = bbase + (BKT_MAX + 1);   // BKT_MAX (doubles as bcnt)
        int* part = bcur + BKT_MAX;          // P
        int* csr = part + P;                 // P

        hipMemsetAsync(bcur, 0, BKT_MAX * sizeof(int), stream);
        k_bhist<<<(P + 4095) / 4096, 256, 0, stream>>>((const int2*)nbr, bcur, P);
        k_bscan<<<1, BKT_MAX, 0, stream>>>(bcur, bbase, bcur, NBKT, P);
        k_partition<<<(P + TILE_A - 1) / TILE_A, 256, 0, stream>>>(
            (const int2*)nbr, bcur, part, P);
        k_bucket<<<NBKT, 256, 0, stream>>>(part, bbase, offs, csr, E, P, NBKT);
        k_agg<<<4096, 256, 0, stream>>>(feat, offs, csr, Kmat, bias, out, E);
    } else if (ws_size >= need_old && NB <= 1024) {
        int* cur = (int*)d_ws;
        int* offs = cur + E;
        int* bsum = offs + E + 1;
        int* csr = bsum + 1024;

        hipMemsetAsync(cur, 0, (size_t)E * sizeof(int), stream);
        k_hist<<<(P + 255) / 256, 256, 0, stream>>>(nbr, cur, P);
        k_blocksum<<<NB, 256, 0, stream>>>(cur, bsum, E);
        k_scan_bsum<<<1, 1024, 0, stream>>>(bsum, NB);
        k_scan_write<<<NB, 256, 0, stream>>>(cur, bsum, offs, cur, E);
        k_build<<<(P + 255) / 256, 256, 0, stream>>>(nbr, cur, csr, P);
        k_agg<<<4096, 256, 0, stream>>>(feat, offs, csr, Kmat, bias, out, E);
    } else {
        hipMemsetAsync(d_out, 0, (size_t)out_size * sizeof(float), stream);
        ea_scatter<<<(P + 3) / 4, 256, 0, stream>>>(feat, nbr, out, P);
        ea_transform<<<2048, 256, 0, stream>>>(out, Kmat, bias, E);
    }
}